// Round 4
// baseline (275.427 us; speedup 1.0000x reference)
//
#include <hip/hip_runtime.h>
#include <math.h>

#define Bx 256
#define Nx 128
#define Dx 512
#define Mx (Bx * Nx)      // 32768 rows
#define NTYPES 6
#define NSTATS 8
#define LN_EPS 1e-5f
#define CAP 8192          // max compacted masked rows (true ~4915)

typedef __attribute__((ext_vector_type(8))) short frag8;   // 8 bf16 (4 VGPRs)
typedef __attribute__((ext_vector_type(4))) float f32x4;   // 4 fp32 acc

__device__ __forceinline__ unsigned short f2bf(float f) {
    unsigned u = __float_as_uint(f);
    u += 0x7fff + ((u >> 16) & 1);   // RNE
    return (unsigned short)(u >> 16);
}
__device__ __forceinline__ float bf2f(unsigned short s) {
    return __uint_as_float((unsigned)s << 16);
}

#define ASYNC16(g, l) __builtin_amdgcn_global_load_lds(                      \
    (const __attribute__((address_space(1))) void*)(g),                      \
    (__attribute__((address_space(3))) void*)(l), 16, 0, 0)

// ws layout (bytes), total ~58 MB
#define EB_OFF    0ULL          // Eb    bf16 [32768][512]  32 MB
#define EC_OFF    33554432ULL   // Ec    bf16 [CAP][512]     8 MB
#define HC_OFF    41943040ULL   // Hc    bf16 [CAP][1024]   16 MB
#define WT_OFF    58720256ULL   // Wtcomb bf16 [1024][512]   1 MB
#define WTC_OFF   59768832ULL   // Wtc    bf16 [512][512]  0.5 MB
#define LIST_OFF  60293120ULL   // list int[32768]
#define POS_OFF   60424192ULL   // pos  int[32768]
#define CNTS_OFF  60555264ULL   // cnts int[256]
#define PACC_OFF  60556288ULL   // pacc float[256][2]
#define PCORR_OFF 60558336ULL   // pcorr float[256]
#define CNTP_OFF  60559360ULL   // cntp int

// 3 weight transposes W[k][n] f32 -> Wt[n][k] bf16, + zero cntp.
__global__ void k_convW_all(const float* __restrict__ W0, const float* __restrict__ W1,
                            const float* __restrict__ W2,
                            unsigned short* __restrict__ T0,
                            unsigned short* __restrict__ T1,
                            unsigned short* __restrict__ T2, int* cntp) {
    if (blockIdx.x == 0 && threadIdx.x == 0) *cntp = 0;
    const int mid = blockIdx.x >> 10;
    const int i = ((blockIdx.x & 1023) << 8) + threadIdx.x;
    const int n = i >> 9, k = i & 511;
    const float* W = (mid == 0) ? W0 : (mid == 1) ? W1 : W2;
    unsigned short* T = (mid == 0) ? T0 : (mid == 1) ? T1 : T2;
    T[i] = f2bf(W[k * Dx + n]);
}

// per batch: compact row list + per-row pos map + per-batch count
__global__ void k_mask_build(const int* __restrict__ m, int* __restrict__ list,
                             int* __restrict__ pos, int* __restrict__ cnts,
                             int* cntp) {
    const int b = blockIdx.x;
    const int t = threadIdx.x;            // 128 threads
    const int r = b * Nx + t;
    const int v = (m[r] != 0) ? 1 : 0;
    const unsigned long long bal = __ballot(v);
    const int wid = t >> 6, lane = t & 63;
    __shared__ int wcnt[2];
    __shared__ int base;
    if (lane == 0) wcnt[wid] = __popcll(bal);
    __syncthreads();
    const int cnt = wcnt[0] + wcnt[1];
    if (t == 0) {
        base = atomicAdd(cntp, cnt);
        cnts[b] = cnt;
    }
    __syncthreads();
    int p = -1;
    if (v) {
        const int rank = __popcll(bal & ((1ULL << lane) - 1)) + (wid ? wcnt[0] : 0);
        p = base + rank;
        if (p < CAP) list[p] = r;
    }
    pos[r] = (p < CAP) ? p : -1;
}

// fused convert + gather: wave per row (4 rows / 256-thr block)
__global__ __launch_bounds__(256) void k_convE_gather(
    const float* __restrict__ e, const int* __restrict__ pos,
    unsigned short* __restrict__ Eb, unsigned short* __restrict__ Ec) {
    const int r = blockIdx.x * 4 + (threadIdx.x >> 6);
    const int lane = threadIdx.x & 63;
    const float4* src = (const float4*)(e + (size_t)r * Dx);
    const float4 a = src[lane * 2];
    const float4 b = src[lane * 2 + 1];
    unsigned short u[8] = {f2bf(a.x), f2bf(a.y), f2bf(a.z), f2bf(a.w),
                           f2bf(b.x), f2bf(b.y), f2bf(b.z), f2bf(b.w)};
    const uint4 v = *(const uint4*)u;
    ((uint4*)(Eb + (size_t)r * Dx))[lane] = v;
    const int p = pos[r];
    if (p >= 0) ((uint4*)(Ec + (size_t)p * Dx))[lane] = v;
}

// head GEMM: Hc = GELU(Ec @ Wtcomb^T + [tb1|sb1]), bf16 out, ldc=1024.
__global__ __launch_bounds__(256) void k_gemm_head(
    const unsigned short* __restrict__ A,
    const unsigned short* __restrict__ Bt,
    const float* __restrict__ bias0, const float* __restrict__ bias1,
    unsigned short* __restrict__ Cout, const int* __restrict__ cntp) {
    const int row0 = blockIdx.y * 128;
    if (row0 >= min(*cntp, CAP)) return;
    __shared__ unsigned short As[128 * 32];
    __shared__ unsigned short Bs[128 * 32];
    const int t = threadIdx.x;
    const int col0 = blockIdx.x * 128;
    const int w = t >> 6, l = t & 63;
    const int wr = (w >> 1) * 64, wcol = (w & 1) * 64;
    const int quad = l >> 4, mr = l & 15;

    const unsigned short* Ag0 = A + (size_t)(row0 + (t >> 2)) * Dx + (t & 3) * 8;
    const unsigned short* Ag1 = Ag0 + (size_t)64 * Dx;
    const unsigned short* Bg0 = Bt + (size_t)(col0 + (t >> 2)) * Dx + (t & 3) * 8;
    const unsigned short* Bg1 = Bg0 + (size_t)64 * Dx;
    unsigned short* Al0 = As + t * 8;
    unsigned short* Al1 = As + (t + 256) * 8;
    unsigned short* Bl0 = Bs + t * 8;
    unsigned short* Bl1 = Bs + (t + 256) * 8;

    f32x4 acc[4][4] = {};
    for (int k0 = 0; k0 < Dx; k0 += 32) {
        __syncthreads();
        ASYNC16(Ag0 + k0, Al0);
        ASYNC16(Ag1 + k0, Al1);
        ASYNC16(Bg0 + k0, Bl0);
        ASYNC16(Bg1 + k0, Bl1);
        __syncthreads();
        frag8 a[4], b[4];
#pragma unroll
        for (int i = 0; i < 4; ++i)
            a[i] = *(const frag8*)&As[(wr + i * 16 + mr) * 32 + quad * 8];
#pragma unroll
        for (int j = 0; j < 4; ++j)
            b[j] = *(const frag8*)&Bs[(wcol + j * 16 + mr) * 32 + quad * 8];
#pragma unroll
        for (int i = 0; i < 4; ++i)
#pragma unroll
            for (int j = 0; j < 4; ++j)
                acc[i][j] = __builtin_amdgcn_mfma_f32_16x16x32_bf16(
                    a[i], b[j], acc[i][j], 0, 0, 0);
    }
#pragma unroll
    for (int i = 0; i < 4; ++i)
#pragma unroll
        for (int j = 0; j < 4; ++j)
#pragma unroll
            for (int r = 0; r < 4; ++r) {
                const int row = row0 + wr + i * 16 + quad * 4 + r;
                const int col = col0 + wcol + j * 16 + mr;
                float v = acc[i][j][r];
                v += (col < 512) ? bias0[col] : bias1[col - 512];
                v = 0.5f * v * (1.0f + erff(v * 0.70710678118654752f));
                Cout[(size_t)row * 1024 + col] = f2bf(v);
            }
}

// Fused both heads epilogue: wave-per-row over compact list.
__global__ __launch_bounds__(256) void k_head2(
    const unsigned short* __restrict__ Hc,
    const float* __restrict__ tg, const float* __restrict__ tbeta,
    const float* __restrict__ tW2, const float* __restrict__ tb2,
    const float* __restrict__ sg, const float* __restrict__ sbeta,
    const float* __restrict__ sW2, const float* __restrict__ sb2,
    const int* __restrict__ list, const int* __restrict__ cntp,
    const int* __restrict__ tgt, const float* __restrict__ stats,
    float* __restrict__ pacc) {
    const int t = threadIdx.x, w = t >> 6, lane = t & 63;
    const int cnt = min(*cntp, CAP);
    float ce_acc = 0.0f, sse_acc = 0.0f;

    for (int idx = blockIdx.x * 4 + w; idx < cnt; idx += gridDim.x * 4) {
        const int r = list[idx];
        const uint4 ut = ((const uint4*)(Hc + (size_t)idx * 1024))[lane];
        const uint4 us = ((const uint4*)(Hc + (size_t)idx * 1024 + 512))[lane];
        float a[8], b8[8];
        {
            const unsigned uu[4] = {ut.x, ut.y, ut.z, ut.w};
            const unsigned vv[4] = {us.x, us.y, us.z, us.w};
#pragma unroll
            for (int j = 0; j < 4; ++j) {
                a[2 * j]      = bf2f((unsigned short)(uu[j] & 0xffff));
                a[2 * j + 1]  = bf2f((unsigned short)(uu[j] >> 16));
                b8[2 * j]     = bf2f((unsigned short)(vv[j] & 0xffff));
                b8[2 * j + 1] = bf2f((unsigned short)(vv[j] >> 16));
            }
        }
        float st = 0, qt = 0, ss = 0, qs = 0;
#pragma unroll
        for (int j = 0; j < 8; ++j) {
            st += a[j]; qt += a[j] * a[j];
            ss += b8[j]; qs += b8[j] * b8[j];
        }
#pragma unroll
        for (int off = 32; off > 0; off >>= 1) {
            st += __shfl_xor(st, off); qt += __shfl_xor(qt, off);
            ss += __shfl_xor(ss, off); qs += __shfl_xor(qs, off);
        }
        const float mt = st * (1.0f / Dx);
        const float rt = rsqrtf(qt * (1.0f / Dx) - mt * mt + LN_EPS);
        const float ms = ss * (1.0f / Dx);
        const float rs = rsqrtf(qs * (1.0f / Dx) - ms * ms + LN_EPS);

        const int c0 = lane * 8;
        float tp[6] = {}, sp[8] = {};
#pragma unroll
        for (int j = 0; j < 8; ++j) {
            const int c = c0 + j;
            const float nt = (a[j] - mt) * rt * tg[c] + tbeta[c];
#pragma unroll
            for (int k = 0; k < 6; ++k) tp[k] += nt * tW2[c * 6 + k];
            const float ns = (b8[j] - ms) * rs * sg[c] + sbeta[c];
#pragma unroll
            for (int k = 0; k < 8; ++k) sp[k] += ns * sW2[c * 8 + k];
        }
#pragma unroll
        for (int k = 0; k < 6; ++k)
#pragma unroll
            for (int off = 32; off > 0; off >>= 1) tp[k] += __shfl_down(tp[k], off);
#pragma unroll
        for (int k = 0; k < 8; ++k)
#pragma unroll
            for (int off = 32; off > 0; off >>= 1) sp[k] += __shfl_down(sp[k], off);

        if (lane == 0) {
            float lg[6];
#pragma unroll
            for (int k = 0; k < 6; ++k) lg[k] = tp[k] + tb2[k];
            float mx = lg[0];
#pragma unroll
            for (int k = 1; k < 6; ++k) mx = fmaxf(mx, lg[k]);
            float se = 0.0f;
#pragma unroll
            for (int k = 0; k < 6; ++k) se += expf(lg[k] - mx);
            ce_acc += -(lg[tgt[r & (Nx - 1)]] - mx - logf(se));
            float sse = 0.0f;
#pragma unroll
            for (int k = 0; k < 8; ++k) {
                const float d = sp[k] + sb2[k] - stats[(size_t)r * NSTATS + k];
                sse += d * d;
            }
            sse_acc += sse;
        }
    }
    __shared__ float red[4][2];
    if (lane == 0) { red[w][0] = ce_acc; red[w][1] = sse_acc; }
    __syncthreads();
    if (t == 0) {
        pacc[2 * blockIdx.x]     = red[0][0] + red[1][0] + red[2][0] + red[3][0];
        pacc[2 * blockIdx.x + 1] = red[0][1] + red[1][1] + red[2][1] + red[3][1];
    }
}

// Fused per-batch: U_b = E_b @ cWt (chunks of 128 cols, direct-global frags,
// C->A layout via LDS), S = U_b @ E_b^T, tanh/diag/masked-SSE -> pcorr[b].
__global__ __launch_bounds__(256) void k_corr_fused(
    const unsigned short* __restrict__ Eb,
    const unsigned short* __restrict__ Wc,   // cWt [e][d] bf16
    const float* __restrict__ Ct,
    const int* __restrict__ m,
    const float* __restrict__ cbp,
    float* __restrict__ pcorr) {
    __shared__ unsigned short Ub[128][136];  // padded rows
    __shared__ float mloc[128];
    __shared__ float red[4];
    const int b = blockIdx.x;
    const int t = threadIdx.x;
    const int w = t >> 6, l = t & 63;
    const int wr = (w >> 1) * 64, wcol = (w & 1) * 64;
    const int quad = l >> 4, mr = l & 15;
    if (t < 128) mloc[t] = (m[b * Nx + t] != 0) ? 1.0f : 0.0f;
    const unsigned short* E = Eb + (size_t)b * Nx * Dx;

    f32x4 S[4][4] = {};
    for (int chunk = 0; chunk < 4; ++chunk) {
        if (chunk) __syncthreads();           // prior stage2 reads done
        // stage1: Uc = E @ Wc[chunk*128 ..][.]^T, frags direct from global (L2)
        f32x4 U[4][4] = {};
        for (int kt = 0; kt < 16; ++kt) {
            frag8 a[4], bf[4];
#pragma unroll
            for (int i = 0; i < 4; ++i)
                a[i] = *(const frag8*)&E[(size_t)(wr + i * 16 + mr) * Dx + kt * 32 + quad * 8];
#pragma unroll
            for (int j = 0; j < 4; ++j)
                bf[j] = *(const frag8*)&Wc[(size_t)(chunk * 128 + wcol + j * 16 + mr) * Dx + kt * 32 + quad * 8];
#pragma unroll
            for (int i = 0; i < 4; ++i)
#pragma unroll
                for (int j = 0; j < 4; ++j)
                    U[i][j] = __builtin_amdgcn_mfma_f32_16x16x32_bf16(
                        a[i], bf[j], U[i][j], 0, 0, 0);
        }
#pragma unroll
        for (int i = 0; i < 4; ++i)
#pragma unroll
            for (int j = 0; j < 4; ++j)
#pragma unroll
                for (int r = 0; r < 4; ++r)
                    Ub[wr + i * 16 + quad * 4 + r][wcol + j * 16 + mr] = f2bf(U[i][j][r]);
        __syncthreads();
        // stage2: S += Uc @ E[:, chunk]^T (A from LDS, B direct from global)
#pragma unroll
        for (int kt = 0; kt < 4; ++kt) {
            frag8 a[4], bf[4];
#pragma unroll
            for (int i = 0; i < 4; ++i)
                a[i] = *(const frag8*)&Ub[wr + i * 16 + mr][kt * 32 + quad * 8];
#pragma unroll
            for (int j = 0; j < 4; ++j)
                bf[j] = *(const frag8*)&E[(size_t)(wcol + j * 16 + mr) * Dx + chunk * 128 + kt * 32 + quad * 8];
#pragma unroll
            for (int i = 0; i < 4; ++i)
#pragma unroll
                for (int j = 0; j < 4; ++j)
                    S[i][j] = __builtin_amdgcn_mfma_f32_16x16x32_bf16(
                        a[i], bf[j], S[i][j], 0, 0, 0);
        }
    }

    const float cb = cbp[0];
    float lsum = 0.0f;
#pragma unroll
    for (int i = 0; i < 4; ++i)
#pragma unroll
        for (int j = 0; j < 4; ++j)
#pragma unroll
            for (int r = 0; r < 4; ++r) {
                const int row = wr + i * 16 + quad * 4 + r;
                const int col = wcol + j * 16 + mr;
                float c = (row == col) ? 1.0f : tanhf(S[i][j][r] + cb);
                const float me = fmaxf(mloc[row], mloc[col]);
                const float d = c - Ct[((size_t)b * Nx + row) * Nx + col];
                lsum += me * d * d;
            }
#pragma unroll
    for (int off = 32; off > 0; off >>= 1) lsum += __shfl_down(lsum, off);
    if (l == 0) red[w] = lsum;
    __syncthreads();
    if (t == 0) pcorr[b] = red[0] + red[1] + red[2] + red[3];
}

__global__ __launch_bounds__(256) void k_final(
    const float* __restrict__ pacc, const float* __restrict__ pcorr,
    const int* __restrict__ cnts, const int* __restrict__ cntp,
    float* __restrict__ out) {
    const int t = threadIdx.x, w = t >> 6, lane = t & 63;
    float ce = pacc[2 * t], sse = pacc[2 * t + 1], co = pcorr[t];
    const int c = cnts[t];
    float me = (float)(Nx * Nx) - (float)((Nx - c) * (Nx - c));
#pragma unroll
    for (int off = 32; off > 0; off >>= 1) {
        ce += __shfl_down(ce, off);
        sse += __shfl_down(sse, off);
        co += __shfl_down(co, off);
        me += __shfl_down(me, off);
    }
    __shared__ float red[4][4];
    if (lane == 0) {
        red[w][0] = ce; red[w][1] = sse; red[w][2] = co; red[w][3] = me;
    }
    __syncthreads();
    if (t == 0) {
        const float CE = red[0][0] + red[1][0] + red[2][0] + red[3][0];
        const float SSE = red[0][1] + red[1][1] + red[2][1] + red[3][1];
        const float CO = red[0][2] + red[1][2] + red[2][2] + red[3][2];
        const float ME = red[0][3] + red[1][3] + red[2][3] + red[3][3];
        const float nm = fmaxf((float)*cntp, 1.0f);
        const float nme = fmaxf(ME, 1.0f);
        out[0] = CE / nm + SSE / (nm * (float)NSTATS) + 0.5f * CO / nme;
    }
}

extern "C" void kernel_launch(void* const* d_in, const int* in_sizes, int n_in,
                              void* d_out, int out_size, void* d_ws, size_t ws_size,
                              hipStream_t stream) {
    const float* e      = (const float*)d_in[0];
    const int*   mcols  = (const int*)d_in[1];
    const int*   ttgt   = (const int*)d_in[2];
    const float* stats  = (const float*)d_in[3];
    const float* corrT  = (const float*)d_in[4];
    const float* tW1    = (const float*)d_in[5];
    const float* tb1    = (const float*)d_in[6];
    const float* tg     = (const float*)d_in[7];
    const float* tbeta  = (const float*)d_in[8];
    const float* tW2    = (const float*)d_in[9];
    const float* tb2    = (const float*)d_in[10];
    const float* sW1    = (const float*)d_in[11];
    const float* sb1    = (const float*)d_in[12];
    const float* sg     = (const float*)d_in[13];
    const float* sbeta  = (const float*)d_in[14];
    const float* sW2    = (const float*)d_in[15];
    const float* sb2    = (const float*)d_in[16];
    const float* cW     = (const float*)d_in[17];
    const float* cb     = (const float*)d_in[18];
    float* out = (float*)d_out;

    char* ws = (char*)d_ws;
    unsigned short* Eb    = (unsigned short*)(ws + EB_OFF);
    unsigned short* Ec    = (unsigned short*)(ws + EC_OFF);
    unsigned short* Hc    = (unsigned short*)(ws + HC_OFF);
    unsigned short* Wtcmb = (unsigned short*)(ws + WT_OFF);
    unsigned short* Wtc   = (unsigned short*)(ws + WTC_OFF);
    int*   list  = (int*)(ws + LIST_OFF);
    int*   pos   = (int*)(ws + POS_OFF);
    int*   cnts  = (int*)(ws + CNTS_OFF);
    float* pacc  = (float*)(ws + PACC_OFF);
    float* pcorr = (float*)(ws + PCORR_OFF);
    int*   cntp  = (int*)(ws + CNTP_OFF);

    k_convW_all<<<3072, 256, 0, stream>>>(tW1, sW1, cW, Wtcmb, Wtcmb + 512 * 512,
                                          Wtc, cntp);
    k_mask_build<<<Bx, Nx, 0, stream>>>(mcols, list, pos, cnts, cntp);
    k_convE_gather<<<Mx / 4, 256, 0, stream>>>(e, pos, Eb, Ec);
    k_gemm_head<<<dim3(8, CAP / 128), 256, 0, stream>>>(Ec, Wtcmb, tb1, sb1, Hc, cntp);
    k_head2<<<256, 256, 0, stream>>>(Hc, tg, tbeta, tW2, tb2, sg, sbeta, sW2, sb2,
                                     list, cntp, ttgt, stats, pacc);
    k_corr_fused<<<Bx, 256, 0, stream>>>(Eb, Wtc, corrT, mcols, cb, pcorr);
    k_final<<<1, 256, 0, stream>>>(pacc, pcorr, cnts, cntp, out);
}

// Round 5
// 254.119 us; speedup vs baseline: 1.0838x; 1.0838x over previous
//
#include <hip/hip_runtime.h>
#include <math.h>

#define Bx 256
#define Nx 128
#define Dx 512
#define Mx (Bx * Nx)      // 32768 rows
#define NTYPES 6
#define NSTATS 8
#define LN_EPS 1e-5f
#define CAP 8192          // max compacted masked rows (true ~4915)

typedef __attribute__((ext_vector_type(8))) short frag8;   // 8 bf16 (4 VGPRs)
typedef __attribute__((ext_vector_type(4))) float f32x4;   // 4 fp32 acc

__device__ __forceinline__ unsigned short f2bf(float f) {
    unsigned u = __float_as_uint(f);
    u += 0x7fff + ((u >> 16) & 1);   // RNE
    return (unsigned short)(u >> 16);
}
__device__ __forceinline__ float bf2f(unsigned short s) {
    return __uint_as_float((unsigned)s << 16);
}

#define ASYNC16(g, l) __builtin_amdgcn_global_load_lds(                      \
    (const __attribute__((address_space(1))) void*)(g),                      \
    (__attribute__((address_space(3))) void*)(l), 16, 0, 0)

// ws layout (bytes), total ~94 MB
#define EB_OFF    0ULL          // Eb  bf16 [32768][512]  32 MB
#define U_OFF     33554432ULL   // U   bf16 [32768][512]  32 MB
#define EC_OFF    67108864ULL   // Ec  bf16 [CAP][512]     8 MB
#define HC_OFF    75497472ULL   // Hc  bf16 [CAP][1024]   16 MB
#define WT_OFF    92274688ULL   // Wtcomb bf16 [1024][512] 1 MB
#define WTC_OFF   93323264ULL   // Wtc    bf16 [512][512] 0.5 MB
#define LIST_OFF  93847552ULL   // list int[32768]
#define POS_OFF   93978624ULL   // pos  int[32768]
#define CNTS_OFF  94109696ULL   // cnts int[256]
#define PACC_OFF  94110720ULL   // pacc float[256][2]
#define PCORR_OFF 94112768ULL   // pcorr float[256]
#define CNTP_OFF  94113792ULL   // cntp int (memset to 0 before k_prep)

// blocks [0,768): 3 weight transposes W[k][n] f32 -> Wt[n][k] bf16 (4 elem/thr)
// blocks [768,1024): per-batch mask compaction (cntp pre-zeroed by memset node)
__global__ __launch_bounds__(256) void k_prep(
    const float* __restrict__ W0, const float* __restrict__ W1,
    const float* __restrict__ W2, unsigned short* __restrict__ Tcmb,
    unsigned short* __restrict__ Tc, const int* __restrict__ m,
    int* __restrict__ list, int* __restrict__ pos, int* __restrict__ cnts,
    int* cntp) {
    if (blockIdx.x >= 768) {
        const int b = blockIdx.x - 768;
        const int t = threadIdx.x;
        const int r = b * Nx + t;
        int v = 0;
        if (t < 128) v = (m[r] != 0) ? 1 : 0;
        const unsigned long long bal = __ballot(v);
        const int wid = t >> 6, lane = t & 63;
        __shared__ int wcnt[2];
        __shared__ int base;
        if (lane == 0 && wid < 2) wcnt[wid] = __popcll(bal);
        __syncthreads();
        const int cnt = wcnt[0] + wcnt[1];
        if (t == 0) {
            base = atomicAdd(cntp, cnt);
            cnts[b] = cnt;
        }
        __syncthreads();
        if (t < 128) {
            int p = -1;
            if (v) {
                const int rank = __popcll(bal & ((1ULL << lane) - 1)) +
                                 (wid ? wcnt[0] : 0);
                p = base + rank;
                if (p < CAP) list[p] = r;
            }
            pos[r] = (p >= 0 && p < CAP) ? p : -1;
        }
        return;
    }
    const int lin = blockIdx.x * 256 + threadIdx.x;   // < 196608
    const int mid = lin >> 16;                        // 65536 threads per matrix
    const int i4  = (lin & 65535) * 4;
    const int n = i4 >> 9, k = i4 & 511;
    const float* W = (mid == 0) ? W0 : (mid == 1) ? W1 : W2;
    unsigned short* T = (mid == 2) ? Tc : (Tcmb + mid * 262144);
    unsigned short o[4];
#pragma unroll
    for (int j = 0; j < 4; ++j) o[j] = f2bf(W[(k + j) * Dx + n]);
    uint2 u;
    u.x = (unsigned)o[0] | ((unsigned)o[1] << 16);
    u.y = (unsigned)o[2] | ((unsigned)o[3] << 16);
    *(uint2*)(T + i4) = u;
}

// fused convert + gather: wave per row (4 rows / 256-thr block)
__global__ __launch_bounds__(256) void k_convE_gather(
    const float* __restrict__ e, const int* __restrict__ pos,
    unsigned short* __restrict__ Eb, unsigned short* __restrict__ Ec) {
    const int r = blockIdx.x * 4 + (threadIdx.x >> 6);
    const int lane = threadIdx.x & 63;
    const int p = pos[r];
    const float4* src = (const float4*)(e + (size_t)r * Dx);
    const float4 a = src[lane * 2];
    const float4 b = src[lane * 2 + 1];
    unsigned short u[8] = {f2bf(a.x), f2bf(a.y), f2bf(a.z), f2bf(a.w),
                           f2bf(b.x), f2bf(b.y), f2bf(b.z), f2bf(b.w)};
    const uint4 v = *(const uint4*)u;
    ((uint4*)(Eb + (size_t)r * Dx))[lane] = v;
    if (p >= 0) ((uint4*)(Ec + (size_t)p * Dx))[lane] = v;
}

// One dispatch, two GEMMs:
// blocks [0,1024):    U = Eb @ Wtc^T           (bf16 out, ldc=512)
// blocks [1024,1536): Hc = GELU(Ec @ Wtcmb^T + [tb1|sb1]) (bf16 out, ldc=1024)
__global__ __launch_bounds__(256) void k_gemms(
    const unsigned short* __restrict__ Eb,
    const unsigned short* __restrict__ Ec,
    const unsigned short* __restrict__ Wtc,
    const unsigned short* __restrict__ Wtcmb,
    const float* __restrict__ bias0, const float* __restrict__ bias1,
    unsigned short* __restrict__ U, unsigned short* __restrict__ Hc,
    const int* __restrict__ cntp) {
    __shared__ unsigned short As[128 * 32];
    __shared__ unsigned short Bs[128 * 32];
    const int bid = blockIdx.x;
    const unsigned short *A, *Bt;
    unsigned short* C;
    int row0, col0, ldc, head;
    if (bid < 1024) {
        A = Eb; Bt = Wtc; C = U;
        row0 = (bid >> 2) << 7; col0 = (bid & 3) << 7;
        ldc = 512; head = 0;
    } else {
        const int b2 = bid - 1024;
        row0 = (b2 >> 3) << 7;
        if (row0 >= min(*cntp, CAP)) return;
        col0 = (b2 & 7) << 7;
        A = Ec; Bt = Wtcmb; C = Hc;
        ldc = 1024; head = 1;
    }
    const int t = threadIdx.x;
    const int w = t >> 6, l = t & 63;
    const int wr = (w >> 1) * 64, wcol = (w & 1) * 64;
    const int quad = l >> 4, mr = l & 15;

    const unsigned short* Ag0 = A + (size_t)(row0 + (t >> 2)) * Dx + (t & 3) * 8;
    const unsigned short* Ag1 = Ag0 + (size_t)64 * Dx;
    const unsigned short* Bg0 = Bt + (size_t)(col0 + (t >> 2)) * Dx + (t & 3) * 8;
    const unsigned short* Bg1 = Bg0 + (size_t)64 * Dx;
    unsigned short* Al0 = As + t * 8;
    unsigned short* Al1 = As + (t + 256) * 8;
    unsigned short* Bl0 = Bs + t * 8;
    unsigned short* Bl1 = Bs + (t + 256) * 8;

    f32x4 acc[4][4] = {};
    for (int k0 = 0; k0 < Dx; k0 += 32) {
        __syncthreads();
        ASYNC16(Ag0 + k0, Al0);
        ASYNC16(Ag1 + k0, Al1);
        ASYNC16(Bg0 + k0, Bl0);
        ASYNC16(Bg1 + k0, Bl1);
        __syncthreads();
        frag8 a[4], b[4];
#pragma unroll
        for (int i = 0; i < 4; ++i)
            a[i] = *(const frag8*)&As[(wr + i * 16 + mr) * 32 + quad * 8];
#pragma unroll
        for (int j = 0; j < 4; ++j)
            b[j] = *(const frag8*)&Bs[(wcol + j * 16 + mr) * 32 + quad * 8];
#pragma unroll
        for (int i = 0; i < 4; ++i)
#pragma unroll
            for (int j = 0; j < 4; ++j)
                acc[i][j] = __builtin_amdgcn_mfma_f32_16x16x32_bf16(
                    a[i], b[j], acc[i][j], 0, 0, 0);
    }
#pragma unroll
    for (int i = 0; i < 4; ++i)
#pragma unroll
        for (int j = 0; j < 4; ++j)
#pragma unroll
            for (int r = 0; r < 4; ++r) {
                const int row = row0 + wr + i * 16 + quad * 4 + r;
                const int col = col0 + wcol + j * 16 + mr;
                float v = acc[i][j][r];
                if (head) {
                    v += (col < 512) ? bias0[col] : bias1[col - 512];
                    v = 0.5f * v * (1.0f + erff(v * 0.70710678118654752f));
                }
                C[(size_t)row * ldc + col] = f2bf(v);
            }
}

// One dispatch, two epilogues:
// blocks [0,256):   per-batch corr: S = U_b @ E_b^T, tanh/diag/masked-SSE
// blocks [256,512): both MLP heads: LN + W2 + CE/MSE over compact list
__global__ __launch_bounds__(256) void k_tail(
    const unsigned short* __restrict__ U,
    const unsigned short* __restrict__ Eb,
    const float* __restrict__ Ct, const int* __restrict__ m,
    const float* __restrict__ cbp, float* __restrict__ pcorr,
    const unsigned short* __restrict__ Hc,
    const float* __restrict__ tg, const float* __restrict__ tbeta,
    const float* __restrict__ tW2, const float* __restrict__ tb2,
    const float* __restrict__ sg, const float* __restrict__ sbeta,
    const float* __restrict__ sW2, const float* __restrict__ sb2,
    const int* __restrict__ list, const int* __restrict__ cntp,
    const int* __restrict__ tgt, const float* __restrict__ stats,
    float* __restrict__ pacc) {
    __shared__ unsigned short As[128 * 32];
    __shared__ unsigned short Bs[128 * 32];
    __shared__ float mloc[128];
    __shared__ float redf[4][2];
    const int t = threadIdx.x;
    const int w = t >> 6, l = t & 63;

    if (blockIdx.x < 256) {
        const int b = blockIdx.x;
        const int wr = (w >> 1) * 64, wcol = (w & 1) * 64;
        const int quad = l >> 4, mr = l & 15;
        if (t < 128) mloc[t] = (m[b * Nx + t] != 0) ? 1.0f : 0.0f;

        const unsigned short* Ub = U + (size_t)b * Nx * Dx;
        const unsigned short* E  = Eb + (size_t)b * Nx * Dx;
        const unsigned short* Ag0 = Ub + (size_t)(t >> 2) * Dx + (t & 3) * 8;
        const unsigned short* Ag1 = Ag0 + (size_t)64 * Dx;
        const unsigned short* Bg0 = E + (size_t)(t >> 2) * Dx + (t & 3) * 8;
        const unsigned short* Bg1 = Bg0 + (size_t)64 * Dx;
        unsigned short* Al0 = As + t * 8;
        unsigned short* Al1 = As + (t + 256) * 8;
        unsigned short* Bl0 = Bs + t * 8;
        unsigned short* Bl1 = Bs + (t + 256) * 8;

        f32x4 acc_r[4][4] = {};
        for (int k0 = 0; k0 < Dx; k0 += 32) {
            __syncthreads();
            ASYNC16(Ag0 + k0, Al0);
            ASYNC16(Ag1 + k0, Al1);
            ASYNC16(Bg0 + k0, Bl0);
            ASYNC16(Bg1 + k0, Bl1);
            __syncthreads();
            frag8 a[4], bfr[4];
#pragma unroll
            for (int i = 0; i < 4; ++i)
                a[i] = *(const frag8*)&As[(wr + i * 16 + mr) * 32 + quad * 8];
#pragma unroll
            for (int j = 0; j < 4; ++j)
                bfr[j] = *(const frag8*)&Bs[(wcol + j * 16 + mr) * 32 + quad * 8];
#pragma unroll
            for (int i = 0; i < 4; ++i)
#pragma unroll
                for (int j = 0; j < 4; ++j)
                    acc_r[i][j] = __builtin_amdgcn_mfma_f32_16x16x32_bf16(
                        a[i], bfr[j], acc_r[i][j], 0, 0, 0);
        }
        const float cb = cbp[0];
        float lsum = 0.0f;
#pragma unroll
        for (int i = 0; i < 4; ++i)
#pragma unroll
            for (int j = 0; j < 4; ++j)
#pragma unroll
                for (int r = 0; r < 4; ++r) {
                    const int row = wr + i * 16 + quad * 4 + r;
                    const int col = wcol + j * 16 + mr;
                    float c = (row == col) ? 1.0f : tanhf(acc_r[i][j][r] + cb);
                    const float me = fmaxf(mloc[row], mloc[col]);
                    const float d = c - Ct[((size_t)b * Nx + row) * Nx + col];
                    lsum += me * d * d;
                }
#pragma unroll
        for (int off = 32; off > 0; off >>= 1) lsum += __shfl_down(lsum, off);
        if (l == 0) redf[w][0] = lsum;
        __syncthreads();
        if (t == 0) pcorr[b] = redf[0][0] + redf[1][0] + redf[2][0] + redf[3][0];
        return;
    }

    // ---- head2 branch ----
    const int blk = blockIdx.x - 256;
    const int cnt = min(*cntp, CAP);
    float ce_acc = 0.0f, sse_acc = 0.0f;
    for (int idx = blk * 4 + w; idx < cnt; idx += 256 * 4) {
        const int r = list[idx];
        const uint4 ut = ((const uint4*)(Hc + (size_t)idx * 1024))[l];
        const uint4 us = ((const uint4*)(Hc + (size_t)idx * 1024 + 512))[l];
        float a[8], b8[8];
        {
            const unsigned uu[4] = {ut.x, ut.y, ut.z, ut.w};
            const unsigned vv[4] = {us.x, us.y, us.z, us.w};
#pragma unroll
            for (int j = 0; j < 4; ++j) {
                a[2 * j]      = bf2f((unsigned short)(uu[j] & 0xffff));
                a[2 * j + 1]  = bf2f((unsigned short)(uu[j] >> 16));
                b8[2 * j]     = bf2f((unsigned short)(vv[j] & 0xffff));
                b8[2 * j + 1] = bf2f((unsigned short)(vv[j] >> 16));
            }
        }
        float st = 0, qt = 0, ss = 0, qs = 0;
#pragma unroll
        for (int j = 0; j < 8; ++j) {
            st += a[j]; qt += a[j] * a[j];
            ss += b8[j]; qs += b8[j] * b8[j];
        }
#pragma unroll
        for (int off = 32; off > 0; off >>= 1) {
            st += __shfl_xor(st, off); qt += __shfl_xor(qt, off);
            ss += __shfl_xor(ss, off); qs += __shfl_xor(qs, off);
        }
        const float mt = st * (1.0f / Dx);
        const float rt = rsqrtf(qt * (1.0f / Dx) - mt * mt + LN_EPS);
        const float ms = ss * (1.0f / Dx);
        const float rs = rsqrtf(qs * (1.0f / Dx) - ms * ms + LN_EPS);

        const int c0 = l * 8;
        float tp[6] = {}, sp[8] = {};
#pragma unroll
        for (int j = 0; j < 8; ++j) {
            const int c = c0 + j;
            const float nt = (a[j] - mt) * rt * tg[c] + tbeta[c];
#pragma unroll
            for (int k = 0; k < 6; ++k) tp[k] += nt * tW2[c * 6 + k];
            const float ns = (b8[j] - ms) * rs * sg[c] + sbeta[c];
#pragma unroll
            for (int k = 0; k < 8; ++k) sp[k] += ns * sW2[c * 8 + k];
        }
#pragma unroll
        for (int k = 0; k < 6; ++k)
#pragma unroll
            for (int off = 32; off > 0; off >>= 1) tp[k] += __shfl_down(tp[k], off);
#pragma unroll
        for (int k = 0; k < 8; ++k)
#pragma unroll
            for (int off = 32; off > 0; off >>= 1) sp[k] += __shfl_down(sp[k], off);

        if (l == 0) {
            float lg[6];
#pragma unroll
            for (int k = 0; k < 6; ++k) lg[k] = tp[k] + tb2[k];
            float mx = lg[0];
#pragma unroll
            for (int k = 1; k < 6; ++k) mx = fmaxf(mx, lg[k]);
            float se = 0.0f;
#pragma unroll
            for (int k = 0; k < 6; ++k) se += expf(lg[k] - mx);
            ce_acc += -(lg[tgt[r & (Nx - 1)]] - mx - logf(se));
            float sse = 0.0f;
#pragma unroll
            for (int k = 0; k < 8; ++k) {
                const float d = sp[k] + sb2[k] - stats[(size_t)r * NSTATS + k];
                sse += d * d;
            }
            sse_acc += sse;
        }
    }
    if (l == 0) { redf[w][0] = ce_acc; redf[w][1] = sse_acc; }
    __syncthreads();
    if (t == 0) {
        pacc[2 * blk]     = redf[0][0] + redf[1][0] + redf[2][0] + redf[3][0];
        pacc[2 * blk + 1] = redf[0][1] + redf[1][1] + redf[2][1] + redf[3][1];
    }
}

__global__ __launch_bounds__(256) void k_final(
    const float* __restrict__ pacc, const float* __restrict__ pcorr,
    const int* __restrict__ cnts, const int* __restrict__ cntp,
    float* __restrict__ out) {
    const int t = threadIdx.x, w = t >> 6, lane = t & 63;
    float ce = pacc[2 * t], sse = pacc[2 * t + 1], co = pcorr[t];
    const int c = cnts[t];
    float me = (float)(Nx * Nx) - (float)((Nx - c) * (Nx - c));
#pragma unroll
    for (int off = 32; off > 0; off >>= 1) {
        ce += __shfl_down(ce, off);
        sse += __shfl_down(sse, off);
        co += __shfl_down(co, off);
        me += __shfl_down(me, off);
    }
    __shared__ float red[4][4];
    if (lane == 0) {
        red[w][0] = ce; red[w][1] = sse; red[w][2] = co; red[w][3] = me;
    }
    __syncthreads();
    if (t == 0) {
        const float CE = red[0][0] + red[1][0] + red[2][0] + red[3][0];
        const float SSE = red[0][1] + red[1][1] + red[2][1] + red[3][1];
        const float CO = red[0][2] + red[1][2] + red[2][2] + red[3][2];
        const float ME = red[0][3] + red[1][3] + red[2][3] + red[3][3];
        const float nm = fmaxf((float)*cntp, 1.0f);
        const float nme = fmaxf(ME, 1.0f);
        out[0] = CE / nm + SSE / (nm * (float)NSTATS) + 0.5f * CO / nme;
    }
}

extern "C" void kernel_launch(void* const* d_in, const int* in_sizes, int n_in,
                              void* d_out, int out_size, void* d_ws, size_t ws_size,
                              hipStream_t stream) {
    const float* e      = (const float*)d_in[0];
    const int*   mcols  = (const int*)d_in[1];
    const int*   ttgt   = (const int*)d_in[2];
    const float* stats  = (const float*)d_in[3];
    const float* corrT  = (const float*)d_in[4];
    const float* tW1    = (const float*)d_in[5];
    const float* tb1    = (const float*)d_in[6];
    const float* tg     = (const float*)d_in[7];
    const float* tbeta  = (const float*)d_in[8];
    const float* tW2    = (const float*)d_in[9];
    const float* tb2    = (const float*)d_in[10];
    const float* sW1    = (const float*)d_in[11];
    const float* sb1    = (const float*)d_in[12];
    const float* sg     = (const float*)d_in[13];
    const float* sbeta  = (const float*)d_in[14];
    const float* sW2    = (const float*)d_in[15];
    const float* sb2    = (const float*)d_in[16];
    const float* cW     = (const float*)d_in[17];
    const float* cb     = (const float*)d_in[18];
    float* out = (float*)d_out;

    char* ws = (char*)d_ws;
    unsigned short* Eb    = (unsigned short*)(ws + EB_OFF);
    unsigned short* U     = (unsigned short*)(ws + U_OFF);
    unsigned short* Ec    = (unsigned short*)(ws + EC_OFF);
    unsigned short* Hc    = (unsigned short*)(ws + HC_OFF);
    unsigned short* Wtcmb = (unsigned short*)(ws + WT_OFF);
    unsigned short* Wtc   = (unsigned short*)(ws + WTC_OFF);
    int*   list  = (int*)(ws + LIST_OFF);
    int*   pos   = (int*)(ws + POS_OFF);
    int*   cnts  = (int*)(ws + CNTS_OFF);
    float* pacc  = (float*)(ws + PACC_OFF);
    float* pcorr = (float*)(ws + PCORR_OFF);
    int*   cntp  = (int*)(ws + CNTP_OFF);

    hipMemsetAsync(cntp, 0, sizeof(int), stream);
    k_prep<<<1024, 256, 0, stream>>>(tW1, sW1, cW, Wtcmb, Wtc, mcols,
                                     list, pos, cnts, cntp);
    k_convE_gather<<<Mx / 4, 256, 0, stream>>>(e, pos, Eb, Ec);
    k_gemms<<<1536, 256, 0, stream>>>(Eb, Ec, Wtc, Wtcmb, tb1, sb1, U, Hc, cntp);
    k_tail<<<512, 256, 0, stream>>>(U, Eb, corrT, mcols, cb, pcorr,
                                    Hc, tg, tbeta, tW2, tb2, sg, sbeta, sW2, sb2,
                                    list, cntp, ttgt, stats, pacc);
    k_final<<<1, 256, 0, stream>>>(pacc, pcorr, cnts, cntp, out);
}

// Round 6
// 240.396 us; speedup vs baseline: 1.1457x; 1.0571x over previous
//
#include <hip/hip_runtime.h>
#include <math.h>

#define Bx 256
#define Nx 128
#define Dx 512
#define Mx (Bx * Nx)      // 32768 rows
#define NTYPES 6
#define NSTATS 8
#define LN_EPS 1e-5f
#define CAP 8192          // max compacted masked rows (true ~4915)

typedef __attribute__((ext_vector_type(8))) short frag8;   // 8 bf16 (4 VGPRs)
typedef __attribute__((ext_vector_type(4))) float f32x4;   // 4 fp32 acc

__device__ __forceinline__ unsigned short f2bf(float f) {
    unsigned u = __float_as_uint(f);
    u += 0x7fff + ((u >> 16) & 1);   // RNE
    return (unsigned short)(u >> 16);
}
__device__ __forceinline__ float bf2f(unsigned short s) {
    return __uint_as_float((unsigned)s << 16);
}

#define ASYNC16(g, l) __builtin_amdgcn_global_load_lds(                      \
    (const __attribute__((address_space(1))) void*)(g),                      \
    (__attribute__((address_space(3))) void*)(l), 16, 0, 0)

// ws layout (bytes), total < 86 MB
#define EB_OFF    0ULL          // Eb  bf16 [32768][512]  32 MB
#define U_OFF     33554432ULL   // U   bf16 [32768][512]  32 MB
#define HC_OFF    67108864ULL   // Hc  bf16 [CAP][1024]   16 MB
#define WT_OFF    83886080ULL   // Wtcomb bf16 [1024][512] 1 MB
#define WTC_OFF   84934656ULL   // Wtc    bf16 [512][512] 0.5 MB
#define LIST_OFF  85458944ULL   // list int[32768]
#define CNTS_OFF  85590016ULL   // cnts int[256]
#define PACC_OFF  85591040ULL   // pacc float[256][2]
#define PCORR_OFF 85593088ULL   // pcorr float[256]
#define CNTP_OFF  85594112ULL   // cntp int (memset to 0 first)

// Mega-prep, one dispatch:
// blocks [0,256):     per-batch mask compaction -> list/cnts/cntp
// blocks [256,1024):  3 weight transposes W[k][n] f32 -> Wt[n][k] bf16
// blocks [1024,9216): E f32 -> bf16 (wave per row, 4 rows/block)
__global__ __launch_bounds__(256) void k_prep(
    const float* __restrict__ e, const float* __restrict__ W0,
    const float* __restrict__ W1, const float* __restrict__ W2,
    unsigned short* __restrict__ Eb, unsigned short* __restrict__ Tcmb,
    unsigned short* __restrict__ Tc, const int* __restrict__ m,
    int* __restrict__ list, int* __restrict__ cnts, int* cntp) {
    const int bid = blockIdx.x;
    const int t = threadIdx.x;
    if (bid < 256) {
        const int b = bid;
        const int r = b * Nx + t;
        int v = 0;
        if (t < 128) v = (m[r] != 0) ? 1 : 0;
        const unsigned long long bal = __ballot(v);
        const int wid = t >> 6, lane = t & 63;
        __shared__ int wcnt[2];
        __shared__ int base;
        if (lane == 0 && wid < 2) wcnt[wid] = __popcll(bal);
        __syncthreads();
        const int cnt = wcnt[0] + wcnt[1];
        if (t == 0) {
            base = atomicAdd(cntp, cnt);
            cnts[b] = cnt;
        }
        __syncthreads();
        if (t < 128 && v) {
            const int rank = __popcll(bal & ((1ULL << lane) - 1)) +
                             (wid ? wcnt[0] : 0);
            const int p = base + rank;
            if (p < CAP) list[p] = r;
        }
        return;
    }
    if (bid < 1024) {
        const int lin = (bid - 256) * 256 + t;            // < 196608
        const int mid = lin >> 16;                        // 65536 per matrix
        const int i4  = (lin & 65535) * 4;
        const int n = i4 >> 9, k = i4 & 511;
        const float* W = (mid == 0) ? W0 : (mid == 1) ? W1 : W2;
        unsigned short* T = (mid == 2) ? Tc : (Tcmb + mid * 262144);
        unsigned short o[4];
#pragma unroll
        for (int j = 0; j < 4; ++j) o[j] = f2bf(W[(k + j) * Dx + n]);
        uint2 u;
        u.x = (unsigned)o[0] | ((unsigned)o[1] << 16);
        u.y = (unsigned)o[2] | ((unsigned)o[3] << 16);
        *(uint2*)(T + i4) = u;
        return;
    }
    const int r = (bid - 1024) * 4 + (t >> 6);
    const int lane = t & 63;
    const float4* src = (const float4*)(e + (size_t)r * Dx);
    const float4 a = src[lane * 2];
    const float4 b = src[lane * 2 + 1];
    unsigned short u[8] = {f2bf(a.x), f2bf(a.y), f2bf(a.z), f2bf(a.w),
                           f2bf(b.x), f2bf(b.y), f2bf(b.z), f2bf(b.w)};
    ((uint4*)(Eb + (size_t)r * Dx))[lane] = *(const uint4*)u;
}

// One dispatch, two GEMMs, BK=64 (two 32-k sub-tiles), 128x128 tiles:
// blocks [0,1024):    U = Eb @ Wtc^T, XCD-swizzled grid (bid = row:5|col:2|xcd:3)
// blocks [1024,1536): Hc = GELU(Eb[list] @ Wtcmb^T + [tb1|sb1]) (indirect gather)
__global__ __launch_bounds__(256) void k_gemms(
    const unsigned short* __restrict__ Eb,
    const unsigned short* __restrict__ Wtc,
    const unsigned short* __restrict__ Wtcmb,
    const float* __restrict__ bias0, const float* __restrict__ bias1,
    unsigned short* __restrict__ U, unsigned short* __restrict__ Hc,
    const int* __restrict__ list, const int* __restrict__ cntp) {
    __shared__ unsigned short As[2 * 4096];   // two 128x32 sub-tiles
    __shared__ unsigned short Bs[2 * 4096];
    const int bid = blockIdx.x;
    const int t = threadIdx.x;
    const unsigned short* Bt;
    unsigned short* C;
    int row0, col0, ldc, head, ra0, ra1;
    if (bid < 1024) {
        // xcd = bid&7, col = (bid>>3)&3, rowgrp = bid>>5; row_tile = rowgrp*8+xcd
        row0 = ((((bid >> 5) << 3) | (bid & 7))) << 7;
        col0 = ((bid >> 3) & 3) << 7;
        Bt = Wtc; C = U; ldc = 512; head = 0;
        ra0 = row0 + (t >> 2);
        ra1 = ra0 + 64;
    } else {
        const int b2 = bid - 1024;
        row0 = (b2 >> 3) << 7;
        const int cnt = min(*cntp, CAP);
        if (row0 >= cnt) return;
        col0 = (b2 & 7) << 7;
        Bt = Wtcmb; C = Hc; ldc = 1024; head = 1;
        ra0 = list[min(row0 + (t >> 2), cnt - 1)];
        ra1 = list[min(row0 + 64 + (t >> 2), cnt - 1)];
    }
    const int w = t >> 6, l = t & 63;
    const int wr = (w >> 1) * 64, wcol = (w & 1) * 64;
    const int quad = l >> 4, mr = l & 15;

    const unsigned short* Ag0 = Eb + (size_t)ra0 * Dx + (t & 3) * 8;
    const unsigned short* Ag1 = Eb + (size_t)ra1 * Dx + (t & 3) * 8;
    const unsigned short* Bg0 = Bt + (size_t)(col0 + (t >> 2)) * Dx + (t & 3) * 8;
    const unsigned short* Bg1 = Bg0 + (size_t)64 * Dx;

    f32x4 acc[4][4] = {};
    for (int k0 = 0; k0 < Dx; k0 += 64) {
        __syncthreads();
#pragma unroll
        for (int s = 0; s < 2; ++s) {
            ASYNC16(Ag0 + k0 + s * 32, As + s * 4096 + t * 8);
            ASYNC16(Ag1 + k0 + s * 32, As + s * 4096 + (t + 256) * 8);
            ASYNC16(Bg0 + k0 + s * 32, Bs + s * 4096 + t * 8);
            ASYNC16(Bg1 + k0 + s * 32, Bs + s * 4096 + (t + 256) * 8);
        }
        __syncthreads();
#pragma unroll
        for (int s = 0; s < 2; ++s) {
            frag8 a[4], b[4];
#pragma unroll
            for (int i = 0; i < 4; ++i)
                a[i] = *(const frag8*)&As[s * 4096 + (wr + i * 16 + mr) * 32 + quad * 8];
#pragma unroll
            for (int j = 0; j < 4; ++j)
                b[j] = *(const frag8*)&Bs[s * 4096 + (wcol + j * 16 + mr) * 32 + quad * 8];
#pragma unroll
            for (int i = 0; i < 4; ++i)
#pragma unroll
                for (int j = 0; j < 4; ++j)
                    acc[i][j] = __builtin_amdgcn_mfma_f32_16x16x32_bf16(
                        a[i], b[j], acc[i][j], 0, 0, 0);
        }
    }
#pragma unroll
    for (int i = 0; i < 4; ++i)
#pragma unroll
        for (int j = 0; j < 4; ++j)
#pragma unroll
            for (int r = 0; r < 4; ++r) {
                const int row = row0 + wr + i * 16 + quad * 4 + r;
                const int col = col0 + wcol + j * 16 + mr;
                float v = acc[i][j][r];
                if (head) {
                    v += (col < 512) ? bias0[col] : bias1[col - 512];
                    v = 0.5f * v * (1.0f + erff(v * 0.70710678118654752f));
                }
                C[(size_t)row * ldc + col] = f2bf(v);
            }
}

// One dispatch, two epilogues:
// blocks [0,256):   per-batch corr: S = U_b @ E_b^T (BK=64), tanh/diag/masked-SSE
// blocks [256,512): both MLP heads: LN + W2 + CE/MSE over compact list
__global__ __launch_bounds__(256) void k_tail(
    const unsigned short* __restrict__ U,
    const unsigned short* __restrict__ Eb,
    const float* __restrict__ Ct, const int* __restrict__ m,
    const float* __restrict__ cbp, float* __restrict__ pcorr,
    const unsigned short* __restrict__ Hc,
    const float* __restrict__ tg, const float* __restrict__ tbeta,
    const float* __restrict__ tW2, const float* __restrict__ tb2,
    const float* __restrict__ sg, const float* __restrict__ sbeta,
    const float* __restrict__ sW2, const float* __restrict__ sb2,
    const int* __restrict__ list, const int* __restrict__ cntp,
    const int* __restrict__ tgt, const float* __restrict__ stats,
    float* __restrict__ pacc) {
    __shared__ unsigned short As[2 * 4096];
    __shared__ unsigned short Bs[2 * 4096];
    __shared__ float mloc[128];
    __shared__ float redf[4][2];
    const int t = threadIdx.x;
    const int w = t >> 6, l = t & 63;

    if (blockIdx.x < 256) {
        const int b = blockIdx.x;
        const int wr = (w >> 1) * 64, wcol = (w & 1) * 64;
        const int quad = l >> 4, mr = l & 15;
        if (t < 128) mloc[t] = (m[b * Nx + t] != 0) ? 1.0f : 0.0f;

        const unsigned short* Ub = U + (size_t)b * Nx * Dx;
        const unsigned short* E  = Eb + (size_t)b * Nx * Dx;
        const unsigned short* Ag0 = Ub + (size_t)(t >> 2) * Dx + (t & 3) * 8;
        const unsigned short* Ag1 = Ag0 + (size_t)64 * Dx;
        const unsigned short* Bg0 = E + (size_t)(t >> 2) * Dx + (t & 3) * 8;
        const unsigned short* Bg1 = Bg0 + (size_t)64 * Dx;

        f32x4 acc_r[4][4] = {};
        for (int k0 = 0; k0 < Dx; k0 += 64) {
            __syncthreads();
#pragma unroll
            for (int s = 0; s < 2; ++s) {
                ASYNC16(Ag0 + k0 + s * 32, As + s * 4096 + t * 8);
                ASYNC16(Ag1 + k0 + s * 32, As + s * 4096 + (t + 256) * 8);
                ASYNC16(Bg0 + k0 + s * 32, Bs + s * 4096 + t * 8);
                ASYNC16(Bg1 + k0 + s * 32, Bs + s * 4096 + (t + 256) * 8);
            }
            __syncthreads();
#pragma unroll
            for (int s = 0; s < 2; ++s) {
                frag8 a[4], bfr[4];
#pragma unroll
                for (int i = 0; i < 4; ++i)
                    a[i] = *(const frag8*)&As[s * 4096 + (wr + i * 16 + mr) * 32 + quad * 8];
#pragma unroll
                for (int j = 0; j < 4; ++j)
                    bfr[j] = *(const frag8*)&Bs[s * 4096 + (wcol + j * 16 + mr) * 32 + quad * 8];
#pragma unroll
                for (int i = 0; i < 4; ++i)
#pragma unroll
                    for (int j = 0; j < 4; ++j)
                        acc_r[i][j] = __builtin_amdgcn_mfma_f32_16x16x32_bf16(
                            a[i], bfr[j], acc_r[i][j], 0, 0, 0);
            }
        }
        const float cb = cbp[0];
        float lsum = 0.0f;
#pragma unroll
        for (int i = 0; i < 4; ++i)
#pragma unroll
            for (int j = 0; j < 4; ++j)
#pragma unroll
                for (int r = 0; r < 4; ++r) {
                    const int row = wr + i * 16 + quad * 4 + r;
                    const int col = wcol + j * 16 + mr;
                    float c = (row == col) ? 1.0f : tanhf(acc_r[i][j][r] + cb);
                    const float me = fmaxf(mloc[row], mloc[col]);
                    const float d = c - Ct[((size_t)b * Nx + row) * Nx + col];
                    lsum += me * d * d;
                }
#pragma unroll
        for (int off = 32; off > 0; off >>= 1) lsum += __shfl_down(lsum, off);
        if (l == 0) redf[w][0] = lsum;
        __syncthreads();
        if (t == 0) pcorr[b] = redf[0][0] + redf[1][0] + redf[2][0] + redf[3][0];
        return;
    }

    // ---- head2 branch ----
    const int blk = blockIdx.x - 256;
    const int cnt = min(*cntp, CAP);
    float ce_acc = 0.0f, sse_acc = 0.0f;
    for (int idx = blk * 4 + w; idx < cnt; idx += 256 * 4) {
        const int r = list[idx];
        const uint4 ut = ((const uint4*)(Hc + (size_t)idx * 1024))[l];
        const uint4 us = ((const uint4*)(Hc + (size_t)idx * 1024 + 512))[l];
        float a[8], b8[8];
        {
            const unsigned uu[4] = {ut.x, ut.y, ut.z, ut.w};
            const unsigned vv[4] = {us.x, us.y, us.z, us.w};
#pragma unroll
            for (int j = 0; j < 4; ++j) {
                a[2 * j]      = bf2f((unsigned short)(uu[j] & 0xffff));
                a[2 * j + 1]  = bf2f((unsigned short)(uu[j] >> 16));
                b8[2 * j]     = bf2f((unsigned short)(vv[j] & 0xffff));
                b8[2 * j + 1] = bf2f((unsigned short)(vv[j] >> 16));
            }
        }
        float st = 0, qt = 0, ss = 0, qs = 0;
#pragma unroll
        for (int j = 0; j < 8; ++j) {
            st += a[j]; qt += a[j] * a[j];
            ss += b8[j]; qs += b8[j] * b8[j];
        }
#pragma unroll
        for (int off = 32; off > 0; off >>= 1) {
            st += __shfl_xor(st, off); qt += __shfl_xor(qt, off);
            ss += __shfl_xor(ss, off); qs += __shfl_xor(qs, off);
        }
        const float mt = st * (1.0f / Dx);
        const float rt = rsqrtf(qt * (1.0f / Dx) - mt * mt + LN_EPS);
        const float ms = ss * (1.0f / Dx);
        const float rs = rsqrtf(qs * (1.0f / Dx) - ms * ms + LN_EPS);

        const int c0 = l * 8;
        float tp[6] = {}, sp[8] = {};
#pragma unroll
        for (int j = 0; j < 8; ++j) {
            const int c = c0 + j;
            const float nt = (a[j] - mt) * rt * tg[c] + tbeta[c];
#pragma unroll
            for (int k = 0; k < 6; ++k) tp[k] += nt * tW2[c * 6 + k];
            const float ns = (b8[j] - ms) * rs * sg[c] + sbeta[c];
#pragma unroll
            for (int k = 0; k < 8; ++k) sp[k] += ns * sW2[c * 8 + k];
        }
#pragma unroll
        for (int k = 0; k < 6; ++k)
#pragma unroll
            for (int off = 32; off > 0; off >>= 1) tp[k] += __shfl_down(tp[k], off);
#pragma unroll
        for (int k = 0; k < 8; ++k)
#pragma unroll
            for (int off = 32; off > 0; off >>= 1) sp[k] += __shfl_down(sp[k], off);

        if (l == 0) {
            float lg[6];
#pragma unroll
            for (int k = 0; k < 6; ++k) lg[k] = tp[k] + tb2[k];
            float mx = lg[0];
#pragma unroll
            for (int k = 1; k < 6; ++k) mx = fmaxf(mx, lg[k]);
            float se = 0.0f;
#pragma unroll
            for (int k = 0; k < 6; ++k) se += expf(lg[k] - mx);
            ce_acc += -(lg[tgt[r & (Nx - 1)]] - mx - logf(se));
            float sse = 0.0f;
#pragma unroll
            for (int k = 0; k < 8; ++k) {
                const float d = sp[k] + sb2[k] - stats[(size_t)r * NSTATS + k];
                sse += d * d;
            }
            sse_acc += sse;
        }
    }
    if (l == 0) { redf[w][0] = ce_acc; redf[w][1] = sse_acc; }
    __syncthreads();
    if (t == 0) {
        pacc[2 * blk]     = redf[0][0] + redf[1][0] + redf[2][0] + redf[3][0];
        pacc[2 * blk + 1] = redf[0][1] + redf[1][1] + redf[2][1] + redf[3][1];
    }
}

__global__ __launch_bounds__(256) void k_final(
    const float* __restrict__ pacc, const float* __restrict__ pcorr,
    const int* __restrict__ cnts, const int* __restrict__ cntp,
    float* __restrict__ out) {
    const int t = threadIdx.x, w = t >> 6, lane = t & 63;
    float ce = pacc[2 * t], sse = pacc[2 * t + 1], co = pcorr[t];
    const int c = cnts[t];
    float me = (float)(Nx * Nx) - (float)((Nx - c) * (Nx - c));
#pragma unroll
    for (int off = 32; off > 0; off >>= 1) {
        ce += __shfl_down(ce, off);
        sse += __shfl_down(sse, off);
        co += __shfl_down(co, off);
        me += __shfl_down(me, off);
    }
    __shared__ float red[4][4];
    if (lane == 0) {
        red[w][0] = ce; red[w][1] = sse; red[w][2] = co; red[w][3] = me;
    }
    __syncthreads();
    if (t == 0) {
        const float CE = red[0][0] + red[1][0] + red[2][0] + red[3][0];
        const float SSE = red[0][1] + red[1][1] + red[2][1] + red[3][1];
        const float CO = red[0][2] + red[1][2] + red[2][2] + red[3][2];
        const float ME = red[0][3] + red[1][3] + red[2][3] + red[3][3];
        const float nm = fmaxf((float)*cntp, 1.0f);
        const float nme = fmaxf(ME, 1.0f);
        out[0] = CE / nm + SSE / (nm * (float)NSTATS) + 0.5f * CO / nme;
    }
}

extern "C" void kernel_launch(void* const* d_in, const int* in_sizes, int n_in,
                              void* d_out, int out_size, void* d_ws, size_t ws_size,
                              hipStream_t stream) {
    const float* e      = (const float*)d_in[0];
    const int*   mcols  = (const int*)d_in[1];
    const int*   ttgt   = (const int*)d_in[2];
    const float* stats  = (const float*)d_in[3];
    const float* corrT  = (const float*)d_in[4];
    const float* tW1    = (const float*)d_in[5];
    const float* tb1    = (const float*)d_in[6];
    const float* tg     = (const float*)d_in[7];
    const float* tbeta  = (const float*)d_in[8];
    const float* tW2    = (const float*)d_in[9];
    const float* tb2    = (const float*)d_in[10];
    const float* sW1    = (const float*)d_in[11];
    const float* sb1    = (const float*)d_in[12];
    const float* sg     = (const float*)d_in[13];
    const float* sbeta  = (const float*)d_in[14];
    const float* sW2    = (const float*)d_in[15];
    const float* sb2    = (const float*)d_in[16];
    const float* cW     = (const float*)d_in[17];
    const float* cb     = (const float*)d_in[18];
    float* out = (float*)d_out;

    char* ws = (char*)d_ws;
    unsigned short* Eb    = (unsigned short*)(ws + EB_OFF);
    unsigned short* U     = (unsigned short*)(ws + U_OFF);
    unsigned short* Hc    = (unsigned short*)(ws + HC_OFF);
    unsigned short* Wtcmb = (unsigned short*)(ws + WT_OFF);
    unsigned short* Wtc   = (unsigned short*)(ws + WTC_OFF);
    int*   list  = (int*)(ws + LIST_OFF);
    int*   cnts  = (int*)(ws + CNTS_OFF);
    float* pacc  = (float*)(ws + PACC_OFF);
    float* pcorr = (float*)(ws + PCORR_OFF);
    int*   cntp  = (int*)(ws + CNTP_OFF);

    hipMemsetAsync(cntp, 0, sizeof(int), stream);
    k_prep<<<9216, 256, 0, stream>>>(e, tW1, sW1, cW, Eb, Wtcmb, Wtc, mcols,
                                     list, cnts, cntp);
    k_gemms<<<1536, 256, 0, stream>>>(Eb, Wtc, Wtcmb, tb1, sb1, U, Hc, list, cntp);
    k_tail<<<512, 256, 0, stream>>>(U, Eb, corrT, mcols, cb, pcorr,
                                    Hc, tg, tbeta, tW2, tb2, sg, sbeta, sW2, sb2,
                                    list, cntp, ttgt, stats, pacc);
    k_final<<<1, 256, 0, stream>>>(pacc, pcorr, cnts, cntp, out);
}